// Round 2
// baseline (164.531 us; speedup 1.0000x reference)
//
#include <hip/hip_runtime.h>
#include <hip/hip_bf16.h>

#define D 8
#define EPS 1e-8f
#define LOG2E_OVER_TAU 2.8853900817779268f   // log2(e) / tau, tau = 0.5
#define LN2 0.6931471805599453f
#define JSPLIT 32

__device__ __forceinline__ float fast_exp2(float x) {
    return __builtin_amdgcn_exp2f(x);
}

// Kernel 1: both projections per row, ELU, normalize.
// u1p = normalize(proj(z_mp)) * (log2e/tau)   [scale folded into mp side]
// u2n = normalize(proj(z_sc))
// ldiag[i] = cos_ii / tau = dot(u1p_i, u2n_i) * ln2
__global__ void proj_kernel(const float* __restrict__ z1f,
                            const float* __restrict__ z2f,
                            const float* __restrict__ W1f,
                            const float* __restrict__ b1f,
                            const float* __restrict__ W2f,
                            const float* __restrict__ b2f,
                            float* __restrict__ u1p,
                            float* __restrict__ u2n,
                            float* __restrict__ ldiag,
                            int N) {
    int n = blockIdx.x * blockDim.x + threadIdx.x;
    if (n >= N) return;

    // uniform weights -> scalar loads, cached
    float W1[D][D], W2[D][D], B1[D], B2[D];
#pragma unroll
    for (int k = 0; k < D; ++k) {
        B1[k] = b1f[k];
        B2[k] = b2f[k];
#pragma unroll
        for (int d2 = 0; d2 < D; ++d2) {
            W1[k][d2] = W1f[k * D + d2];
            W2[k][d2] = W2f[k * D + d2];
        }
    }

    // 8 floats per row = 32 B: two float4 loads each
    const float4* z1v = (const float4*)z1f + 2 * n;
    const float4* z2v = (const float4*)z2f + 2 * n;
    float4 r1a = z1v[0], r1b = z1v[1];
    float4 r2a = z2v[0], r2b = z2v[1];
    float z1[D] = {r1a.x, r1a.y, r1a.z, r1a.w, r1b.x, r1b.y, r1b.z, r1b.w};
    float z2[D] = {r2a.x, r2a.y, r2a.z, r2a.w, r2b.x, r2b.y, r2b.z, r2b.w};

    // layer 1 + ELU (alpha = 1)
    float h1[D], h2[D];
#pragma unroll
    for (int k = 0; k < D; ++k) {
        float t1 = B1[k], t2 = B1[k];
#pragma unroll
        for (int d2 = 0; d2 < D; ++d2) {
            t1 = fmaf(z1[d2], W1[k][d2], t1);
            t2 = fmaf(z2[d2], W1[k][d2], t2);
        }
        h1[k] = (t1 > 0.f) ? t1 : (expf(t1) - 1.f);
        h2[k] = (t2 > 0.f) ? t2 : (expf(t2) - 1.f);
    }

    // layer 2 + squared norms
    float p1[D], p2[D];
    float sq1 = 0.f, sq2 = 0.f;
#pragma unroll
    for (int o = 0; o < D; ++o) {
        float t1 = B2[o], t2 = B2[o];
#pragma unroll
        for (int k = 0; k < D; ++k) {
            t1 = fmaf(h1[k], W2[o][k], t1);
            t2 = fmaf(h2[k], W2[o][k], t2);
        }
        p1[o] = t1; p2[o] = t2;
        sq1 = fmaf(t1, t1, sq1);
        sq2 = fmaf(t2, t2, sq2);
    }
    float s1 = LOG2E_OVER_TAU * rsqrtf(sq1);
    float s2 = rsqrtf(sq2);

    float a[D], b[D];
    float dacc = 0.f;
#pragma unroll
    for (int o = 0; o < D; ++o) {
        a[o] = p1[o] * s1;
        b[o] = p2[o] * s2;
        dacc = fmaf(a[o], b[o], dacc);
    }
    // vectorized stores: 2x float4 per row
    float4* u1v = (float4*)u1p + 2 * n;
    float4* u2v = (float4*)u2n + 2 * n;
    u1v[0] = make_float4(a[0], a[1], a[2], a[3]);
    u1v[1] = make_float4(a[4], a[5], a[6], a[7]);
    u2v[0] = make_float4(b[0], b[1], b[2], b[3]);
    u2v[1] = make_float4(b[4], b[5], b[6], b[7]);
    ldiag[n] = dacc * LN2;   // log(diag_i) = cos_ii / tau
}

// Kernel 2: partial row sums of exp2(A_i . B_j) over a j-chunk.
// Lane owns row i (8 floats in VGPRs); B accesses are wave-uniform.
__global__ void pair_rowsum_kernel(const float* __restrict__ A,
                                   const float* __restrict__ B,
                                   float* __restrict__ outsum,
                                   int N, int jChunk) {
    int i = blockIdx.x * blockDim.x + threadIdx.x;
    int j0 = blockIdx.y * jChunk;
    int j1 = min(N, j0 + jChunk);

    float a[D];
    if (i < N) {
        float4 v0 = *((const float4*)A + 2 * i);
        float4 v1 = *((const float4*)A + 2 * i + 1);
        a[0] = v0.x; a[1] = v0.y; a[2] = v0.z; a[3] = v0.w;
        a[4] = v1.x; a[5] = v1.y; a[6] = v1.z; a[7] = v1.w;
    } else {
#pragma unroll
        for (int d2 = 0; d2 < D; ++d2) a[d2] = 0.f;
    }

    const float4* B4 = (const float4*)B;
    float acc = 0.f;
#pragma unroll 4
    for (int j = j0; j < j1; ++j) {
        float4 b0 = B4[2 * j];
        float4 b1v = B4[2 * j + 1];
        float d = a[0] * b0.x;
        d = fmaf(a[1], b0.y, d);
        d = fmaf(a[2], b0.z, d);
        d = fmaf(a[3], b0.w, d);
        d = fmaf(a[4], b1v.x, d);
        d = fmaf(a[5], b1v.y, d);
        d = fmaf(a[6], b1v.z, d);
        d = fmaf(a[7], b1v.w, d);
        acc += fast_exp2(d);
    }
    if (i < N) atomicAdd(&outsum[i], acc);
}

// Kernel 3: loss = mean_i[ 0.5*log(rs_i+eps) + 0.5*log(cs_i+eps) - ldiag_i ]
__global__ void finalize_kernel(const float* __restrict__ rs,
                                const float* __restrict__ cs,
                                const float* __restrict__ ldiag,
                                float* __restrict__ out,
                                int N) {
    int tid = threadIdx.x;
    float acc = 0.f;
    for (int i = tid; i < N; i += blockDim.x) {
        acc += 0.5f * __logf(rs[i] + EPS) + 0.5f * __logf(cs[i] + EPS) - ldiag[i];
    }
#pragma unroll
    for (int off = 32; off > 0; off >>= 1)
        acc += __shfl_down(acc, off, 64);
    __shared__ float wsum[4];
    int wave = tid >> 6;
    if ((tid & 63) == 0) wsum[wave] = acc;
    __syncthreads();
    if (tid == 0) {
        float total = wsum[0] + wsum[1] + wsum[2] + wsum[3];
        out[0] = total / (float)N;
    }
}

extern "C" void kernel_launch(void* const* d_in, const int* in_sizes, int n_in,
                              void* d_out, int out_size, void* d_ws, size_t ws_size,
                              hipStream_t stream) {
    const float* z1 = (const float*)d_in[0];  // z_mp [N,8] f32
    const float* z2 = (const float*)d_in[1];  // z_sc [N,8] f32
    const float* W1 = (const float*)d_in[2];  // [8,8]
    const float* b1 = (const float*)d_in[3];  // [8]
    const float* W2 = (const float*)d_in[4];  // [8,8]
    const float* b2 = (const float*)d_in[5];  // [8]
    int N = in_sizes[0] / D;  // 10000

    float* ws = (float*)d_ws;
    float* u1p   = ws;                      // N*8
    float* u2n   = u1p + (size_t)N * D;     // N*8
    float* ldiag = u2n + (size_t)N * D;     // N
    float* rs    = ldiag + N;               // N
    float* cs    = rs + N;                  // N

    // ws is re-poisoned 0xAA before every timed launch: zero the accumulators
    hipMemsetAsync(rs, 0, sizeof(float) * 2 * (size_t)N, stream);

    int blocks = (N + 255) / 256;
    proj_kernel<<<blocks, 256, 0, stream>>>(z1, z2, W1, b1, W2, b2,
                                            u1p, u2n, ldiag, N);

    int jChunk = (N + JSPLIT - 1) / JSPLIT;
    dim3 pgrid(blocks, JSPLIT);
    // row sums: m[i][j] over j
    pair_rowsum_kernel<<<pgrid, 256, 0, stream>>>(u1p, u2n, rs, N, jChunk);
    // col sums: row sums of the transpose (scale factor lives inside the dot)
    pair_rowsum_kernel<<<pgrid, 256, 0, stream>>>(u2n, u1p, cs, N, jChunk);

    finalize_kernel<<<1, 256, 0, stream>>>(rs, cs, ldiag, (float*)d_out, N);
}

// Round 3
// 120.839 us; speedup vs baseline: 1.3616x; 1.3616x over previous
//
#include <hip/hip_runtime.h>
#include <hip/hip_bf16.h>

#define D 8
#define EPS 1e-8f
#define LOG2E_OVER_TAU 2.8853900817779268f   // log2(e) / tau, tau = 0.5
#define LN2 0.6931471805599453f
#define RTILE 8                               // rows per lane in fused kernel
#define WROWS (RTILE * 64)                    // rows per wave = 512
#define BROWS (WROWS * 4)                     // rows per block (4 waves) = 2048
#define JSPLIT 200

__device__ __forceinline__ float fast_exp2(float x) {
    return __builtin_amdgcn_exp2f(x);
}

// Kernel 1: both projections per row, ELU, normalize; also zero accumulators.
// u1p = normalize(proj(z_mp)) * (log2e/tau)   [scale folded into mp side]
// u2n = normalize(proj(z_sc))
// ldiag[i] = cos_ii / tau = dot(u1p_i, u2n_i) * ln2
__global__ void proj_kernel(const float* __restrict__ z1f,
                            const float* __restrict__ z2f,
                            const float* __restrict__ W1f,
                            const float* __restrict__ b1f,
                            const float* __restrict__ W2f,
                            const float* __restrict__ b2f,
                            float* __restrict__ u1p,
                            float* __restrict__ u2n,
                            float* __restrict__ ldiag,
                            float* __restrict__ rs,
                            float* __restrict__ cs,
                            float* __restrict__ out,
                            int N) {
    int n = blockIdx.x * blockDim.x + threadIdx.x;
    if (n >= N) return;
    rs[n] = 0.f;                 // replaces the hipMemsetAsync dispatch
    cs[n] = 0.f;
    if (n == 0) out[0] = 0.f;    // finalize atomically accumulates into out

    float W1[D][D], W2[D][D], B1[D], B2[D];
#pragma unroll
    for (int k = 0; k < D; ++k) {
        B1[k] = b1f[k];
        B2[k] = b2f[k];
#pragma unroll
        for (int d2 = 0; d2 < D; ++d2) {
            W1[k][d2] = W1f[k * D + d2];
            W2[k][d2] = W2f[k * D + d2];
        }
    }

    const float4* z1v = (const float4*)z1f + 2 * n;
    const float4* z2v = (const float4*)z2f + 2 * n;
    float4 r1a = z1v[0], r1b = z1v[1];
    float4 r2a = z2v[0], r2b = z2v[1];
    float z1[D] = {r1a.x, r1a.y, r1a.z, r1a.w, r1b.x, r1b.y, r1b.z, r1b.w};
    float z2[D] = {r2a.x, r2a.y, r2a.z, r2a.w, r2b.x, r2b.y, r2b.z, r2b.w};

    float h1[D], h2[D];
#pragma unroll
    for (int k = 0; k < D; ++k) {
        float t1 = B1[k], t2 = B1[k];
#pragma unroll
        for (int d2 = 0; d2 < D; ++d2) {
            t1 = fmaf(z1[d2], W1[k][d2], t1);
            t2 = fmaf(z2[d2], W1[k][d2], t2);
        }
        h1[k] = (t1 > 0.f) ? t1 : (expf(t1) - 1.f);
        h2[k] = (t2 > 0.f) ? t2 : (expf(t2) - 1.f);
    }

    float p1[D], p2[D];
    float sq1 = 0.f, sq2 = 0.f;
#pragma unroll
    for (int o = 0; o < D; ++o) {
        float t1 = B2[o], t2 = B2[o];
#pragma unroll
        for (int k = 0; k < D; ++k) {
            t1 = fmaf(h1[k], W2[o][k], t1);
            t2 = fmaf(h2[k], W2[o][k], t2);
        }
        p1[o] = t1; p2[o] = t2;
        sq1 = fmaf(t1, t1, sq1);
        sq2 = fmaf(t2, t2, sq2);
    }
    float s1 = LOG2E_OVER_TAU * rsqrtf(sq1);
    float s2 = rsqrtf(sq2);

    float a[D], b[D];
    float dacc = 0.f;
#pragma unroll
    for (int o = 0; o < D; ++o) {
        a[o] = p1[o] * s1;
        b[o] = p2[o] * s2;
        dacc = fmaf(a[o], b[o], dacc);
    }
    float4* u1v = (float4*)u1p + 2 * n;
    float4* u2v = (float4*)u2n + 2 * n;
    u1v[0] = make_float4(a[0], a[1], a[2], a[3]);
    u1v[1] = make_float4(a[4], a[5], a[6], a[7]);
    u2v[0] = make_float4(b[0], b[1], b[2], b[3]);
    u2v[1] = make_float4(b[4], b[5], b[6], b[7]);
    ldiag[n] = dacc * LN2;   // log(diag_i) = cos_ii / tau
}

// Kernel 2 (fused): each exp computed ONCE, feeding both row sums (register
// accumulators, 8 rows/lane) and col sums (wave shuffle-reduction + atomic).
// Out-of-range rows have a=0 -> e=exp2(0)=1; their contamination of the
// column reduction is exactly the (uniform) invalid-row count, subtracted.
__global__ __launch_bounds__(256) void pair_fused_kernel(
        const float* __restrict__ A,   // u1p (scale folded in)
        const float* __restrict__ B,   // u2n
        float* __restrict__ rs,
        float* __restrict__ cs,
        int N, int jChunk) {
    int tid = threadIdx.x;
    int lane = tid & 63;
    int wave = tid >> 6;
    int iw0 = blockIdx.x * BROWS + wave * WROWS;   // first row of this wave

    // load 8 rows, strided by 64 for coalescing: row_k = iw0 + k*64 + lane
    float a[RTILE][D];
#pragma unroll
    for (int k = 0; k < RTILE; ++k) {
        int r = iw0 + k * 64 + lane;
        if (r < N) {
            float4 v0 = ((const float4*)A)[2 * r];
            float4 v1 = ((const float4*)A)[2 * r + 1];
            a[k][0] = v0.x; a[k][1] = v0.y; a[k][2] = v0.z; a[k][3] = v0.w;
            a[k][4] = v1.x; a[k][5] = v1.y; a[k][6] = v1.z; a[k][7] = v1.w;
        } else {
#pragma unroll
            for (int d2 = 0; d2 < D; ++d2) a[k][d2] = 0.f;
        }
    }
    int validRows = N - iw0;
    if (validRows < 0) validRows = 0;
    if (validRows > WROWS) validRows = WROWS;
    float invf = (float)(WROWS - validRows);   // wave-uniform

    int j0 = blockIdx.y * jChunk;
    int j1 = min(N, j0 + jChunk);

    float acc[RTILE];
#pragma unroll
    for (int k = 0; k < RTILE; ++k) acc[k] = 0.f;

    const float4* B4 = (const float4*)B;
    for (int j = j0; j < j1; ++j) {
        float4 b0 = B4[2 * j];
        float4 b1v = B4[2 * j + 1];
        float csum = 0.f;
#pragma unroll
        for (int k = 0; k < RTILE; ++k) {
            float d = a[k][0] * b0.x;
            d = fmaf(a[k][1], b0.y, d);
            d = fmaf(a[k][2], b0.z, d);
            d = fmaf(a[k][3], b0.w, d);
            d = fmaf(a[k][4], b1v.x, d);
            d = fmaf(a[k][5], b1v.y, d);
            d = fmaf(a[k][6], b1v.z, d);
            d = fmaf(a[k][7], b1v.w, d);
            float e = fast_exp2(d);
            acc[k] += e;
            csum += e;
        }
        // wave-wide sum of csum (64 lanes)
#pragma unroll
        for (int m = 1; m < 64; m <<= 1)
            csum += __shfl_xor(csum, m, 64);
        if (lane == 0)
            atomicAdd(&cs[j], csum - invf);
    }

#pragma unroll
    for (int k = 0; k < RTILE; ++k) {
        int r = iw0 + k * 64 + lane;
        if (r < N) atomicAdd(&rs[r], acc[k]);
    }
}

// Kernel 3: loss = mean_i[ 0.5*log(rs_i+eps) + 0.5*log(cs_i+eps) - ldiag_i ]
__global__ void finalize_kernel(const float* __restrict__ rs,
                                const float* __restrict__ cs,
                                const float* __restrict__ ldiag,
                                float* __restrict__ out,
                                int N) {
    int gid = blockIdx.x * blockDim.x + threadIdx.x;
    int stride = gridDim.x * blockDim.x;
    float acc = 0.f;
    for (int i = gid; i < N; i += stride) {
        acc += 0.5f * __logf(rs[i] + EPS) + 0.5f * __logf(cs[i] + EPS) - ldiag[i];
    }
#pragma unroll
    for (int off = 32; off > 0; off >>= 1)
        acc += __shfl_down(acc, off, 64);
    __shared__ float wsum[4];
    int wave = threadIdx.x >> 6;
    if ((threadIdx.x & 63) == 0) wsum[wave] = acc;
    __syncthreads();
    if (threadIdx.x == 0) {
        float total = wsum[0] + wsum[1] + wsum[2] + wsum[3];
        atomicAdd(out, total / (float)N);
    }
}

extern "C" void kernel_launch(void* const* d_in, const int* in_sizes, int n_in,
                              void* d_out, int out_size, void* d_ws, size_t ws_size,
                              hipStream_t stream) {
    const float* z1 = (const float*)d_in[0];  // z_mp [N,8] f32
    const float* z2 = (const float*)d_in[1];  // z_sc [N,8] f32
    const float* W1 = (const float*)d_in[2];  // [8,8]
    const float* b1 = (const float*)d_in[3];  // [8]
    const float* W2 = (const float*)d_in[4];  // [8,8]
    const float* b2 = (const float*)d_in[5];  // [8]
    int N = in_sizes[0] / D;  // 10000

    float* ws = (float*)d_ws;
    float* u1p   = ws;                      // N*8
    float* u2n   = u1p + (size_t)N * D;     // N*8
    float* ldiag = u2n + (size_t)N * D;     // N
    float* rs    = ldiag + N;               // N
    float* cs    = rs + N;                  // N
    float* out   = (float*)d_out;

    int blocks = (N + 255) / 256;
    proj_kernel<<<blocks, 256, 0, stream>>>(z1, z2, W1, b1, W2, b2,
                                            u1p, u2n, ldiag, rs, cs, out, N);

    int iBlocks = (N + BROWS - 1) / BROWS;               // 5 for N=10000
    int jChunk = (N + JSPLIT - 1) / JSPLIT;              // 50
    dim3 pgrid(iBlocks, JSPLIT);                         // 1000 blocks
    pair_fused_kernel<<<pgrid, 256, 0, stream>>>(u1p, u2n, rs, cs, N, jChunk);

    finalize_kernel<<<10, 256, 0, stream>>>(rs, cs, ldiag, out, N);
}